// Round 13
// baseline (87.688 us; speedup 1.0000x reference)
//
#include <hip/hip_runtime.h>

#define D      4096
#define NERR   8192
#define DF4    (D / 4)       // 1024 f4 per row
#define HROWS  (NERR / 2)    // 4096 rows per half
#define TPB    512
#define NBLK   256
#define NK     64            // row-groups per thread (rows r0 + 64k)
#define NREG   40            // row-groups staged in registers (160 VGPR)
#define NLDS   7             // row-groups staged in LDS (57 KB)
#define NSTAGE (NREG + NLDS) // 47; remaining 17 re-read via IF$

typedef float f32x4 __attribute__((ext_vector_type(4)));

// Persistent fused kernel. Block b: strip s=b>>1 (f4-cols 8s..8s+8 = 32 cols,
// 128 B/row), half h=b&1 (rows 4096h..+4096) — R9's decomposition. e is staged
// in regs/LDS across a homemade grid barrier, eliminating 73% of the phase-2
// fabric re-read. 1 block/CU (VGPR-bound) => all 256 blocks resident => the
// global spin barrier cannot deadlock.
__global__ __launch_bounds__(TPB, 2) void k_fused(const f32x4* __restrict__ e4,
                                                  const f32x4* __restrict__ c4,
                                                  f32x4* __restrict__ oc4,
                                                  f32x4* __restrict__ top4,
                                                  f32x4* __restrict__ bot4,
                                                  float* __restrict__ partf,
                                                  int*   __restrict__ bar) {
    __shared__ f32x4 stage[NLDS * TPB];   // 57344 B, [k][t] => conflict-free
    __shared__ f32x4 wred[8 * 8];
    __shared__ float aptL[32];
    __shared__ f32x4 scl[8];
    __shared__ f32x4 muL[8];

    const int t    = threadIdx.x;
    const int lane = t & 63;
    const int w    = t >> 6;            // 8 waves
    const int cf   = t & 7;             // f4-col within strip
    const int r0   = t >> 3;            // 0..63
    const int s    = blockIdx.x >> 1;
    const int h    = blockIdx.x & 1;
    const int off  = s * 8 + cf;
    const size_t rbase = (size_t)h * HROWS;

    // ---- phase 1: read strip-half once; stage + accumulate |e| ----------
    f32x4 reg[NREG];
    f32x4 acc = (f32x4)(0.f, 0.f, 0.f, 0.f);
    #pragma unroll
    for (int k = 0; k < NK; ++k) {
        f32x4 v = e4[(rbase + (size_t)k * 64 + r0) * DF4 + off];
        acc.x += fabsf(v.x);
        acc.y += fabsf(v.y);
        acc.z += fabsf(v.z);
        acc.w += fabsf(v.w);
        if (k < NREG)         reg[k] = v;
        else if (k < NSTAGE)  stage[(k - NREG) * TPB + t] = v;
        // k >= NSTAGE: re-read in phase 2 (IF$-served)
    }
    #pragma unroll
    for (int st = 8; st <= 32; st <<= 1) {
        acc.x += __shfl_xor(acc.x, st, 64);
        acc.y += __shfl_xor(acc.y, st, 64);
        acc.z += __shfl_xor(acc.z, st, 64);
        acc.w += __shfl_xor(acc.w, st, 64);
    }
    if (lane < 8) wred[w * 8 + lane] = acc;
    __syncthreads();

    if (t < 32) {                       // publish 32-float partial, agent scope
        const int f4 = t >> 2, cm = t & 3;
        float sum = 0.f;
        #pragma unroll
        for (int w2 = 0; w2 < 8; ++w2) sum += wred[w2 * 8 + f4][cm];
        __hip_atomic_store(&partf[(size_t)blockIdx.x * 32 + t], sum,
                           __ATOMIC_RELAXED, __HIP_MEMORY_SCOPE_AGENT);
    }
    __syncthreads();

    // ---- grid barrier (single-use; bar[0] memset to 0 before launch) ----
    if (t == 0) {
        __hip_atomic_fetch_add(&bar[0], 1, __ATOMIC_ACQ_REL,
                               __HIP_MEMORY_SCOPE_AGENT);
        while (__hip_atomic_load(&bar[0], __ATOMIC_ACQUIRE,
                                 __HIP_MEMORY_SCOPE_AGENT) < NBLK) {}
    }
    __syncthreads();

    if (t < 32)
        aptL[t] = __hip_atomic_load(&partf[(size_t)(2 * s) * 32 + t],
                                    __ATOMIC_RELAXED, __HIP_MEMORY_SCOPE_AGENT)
                + __hip_atomic_load(&partf[(size_t)(2 * s + 1) * 32 + t],
                                    __ATOMIC_RELAXED, __HIP_MEMORY_SCOPE_AGENT);
    __syncthreads();

    // ---- finalize (redundant in both halves; 8 threads x 4 cols) --------
    if (t < 8) {
        const int g = s * 8 + t;
        const f32x4 cen = c4[g];
        f32x4 oc, cs, mu4;
        #pragma unroll
        for (int j = 0; j < 4; ++j) {
            const float apt = aptL[t * 4 + j];
            const float c  = cen[j];
            const float ub = c + apt;
            const float lb = c - apt;
            const bool cross = (ub > 0.f) && (lb < 0.f);
            const bool act   = (lb >= 0.f);
            const float denom = cross ? (ub - lb) : 1.f;
            const float slope = cross ? (ub / denom) : 0.f;
            const float mu    = cross ? (-slope * lb * 0.5f) : 0.f;
            oc[j]  = act ? c : (slope * c + mu);
            cs[j]  = act ? 1.f : slope;
            mu4[j] = mu;
        }
        scl[t] = cs;
        muL[t] = mu4;
        if (h == 0) oc4[g] = oc;
    }
    __syncthreads();

    const f32x4 cs = scl[cf];

    // ---- phase 2a: staged-register rows -> top (pure NT write) ----------
    #pragma unroll
    for (int k = 0; k < NREG; ++k) {
        f32x4 v = reg[k] * cs;
        __builtin_nontemporal_store(
            v, &top4[(rbase + (size_t)k * 64 + r0) * DF4 + off]);
    }
    // ---- phase 2b: staged-LDS rows -> top (pure NT write) ---------------
    #pragma unroll
    for (int k = NREG; k < NSTAGE; ++k) {
        f32x4 v = stage[(k - NREG) * TPB + t] * cs;
        __builtin_nontemporal_store(
            v, &top4[(rbase + (size_t)k * 64 + r0) * DF4 + off]);
    }
    // ---- phase 2c: bottom rows [32s+16h, +16) (pure NT write) -----------
    {
        const int r   = 32 * s + 16 * h + (t >> 5);
        const int dg  = r >> 2;                 // diag f4-col of row r
        const float muv = muL[(r >> 2) - 8 * s][r & 3];
        const int c0  = t & 31;
        #pragma unroll
        for (int j = 0; j < 32; ++j) {
            const int c = c0 + j * 32;
            f32x4 v = (f32x4)(0.f, 0.f, 0.f, 0.f);
            if (c == dg) v[r & 3] = muv;
            __builtin_nontemporal_store(v, &bot4[(size_t)r * DF4 + c]);
        }
    }
    // ---- phase 2d: unstaged rows: re-read (IF$) + NT write (mixed tail) -
    #pragma unroll
    for (int k = NSTAGE; k < NK; ++k) {
        const size_t idx = (rbase + (size_t)k * 64 + r0) * DF4 + off;
        f32x4 v = e4[idx] * cs;
        __builtin_nontemporal_store(v, &top4[idx]);
    }
}

extern "C" void kernel_launch(void* const* d_in, const int* in_sizes, int n_in,
                              void* d_out, int out_size, void* d_ws, size_t ws_size,
                              hipStream_t stream) {
    const float* center = (const float*)d_in[0];   // (4096,)
    const float* error  = (const float*)d_in[1];   // (8192, 4096)
    float* out = (float*)d_out;
    float* ws  = (float*)d_ws;

    // ws: [partf: 256*32 floats = 32 KB][bar: 1 int]
    float* partf = ws;
    int*   bar   = (int*)(ws + NBLK * 32);

    float* out_center = out;                                   // (4096,)
    float* out_top    = out + D;                               // (8192, 4096)
    float* out_bottom = out + (size_t)D + (size_t)NERR * D;    // (4096, 4096)

    // Barrier counter must be 0 at kernel start on every call (ws poisoned
    // 0xAA once, never re-poisoned). Tiny async memset is graph-capture-safe.
    hipMemsetAsync(bar, 0, sizeof(int), stream);

    k_fused<<<NBLK, TPB, 0, stream>>>(
        (const f32x4*)error, (const f32x4*)center,
        (f32x4*)out_center, (f32x4*)out_top, (f32x4*)out_bottom,
        partf, bar);
}

// Round 14
// 85.387 us; speedup vs baseline: 1.0269x; 1.0269x over previous
//
#include <hip/hip_runtime.h>

#define D      4096
#define NERR   8192
#define DF4    (D / 4)       // 1024 f4 per row
#define HROWS  (NERR / 2)    // 4096 rows per half
#define TPB    512
#define NBLK   256
#define NK     64            // row-groups per thread (rows r0 + 64k)
#define NREG   45            // staged in registers (180 VGPR)
#define NLDS   (NK - NREG)   // 19 staged in LDS (152 KB) -> NOTHING re-read

typedef float f32x4 __attribute__((ext_vector_type(4)));

// Persistent fused kernel, R9 decomposition: block b = strip s=b>>1
// (f4-cols 8s..8s+8 = 32 cols, 128 B/row) x half h=b&1 (rows 4096h..+4096).
// ALL of e is staged on-chip (45 reg + 19 LDS row-groups per thread) across
// the grid barrier -> phase 2 is pure NT-write; e crosses the fabric once.
// amdgpu_waves_per_eu(2,2): pin 2 waves/EU = 1 block/CU, full 256-VGPR
// budget, no spill-for-occupancy (R13's failure). 256 blocks = 256 CUs,
// all resident -> spin barrier deadlock-free.
__global__ __launch_bounds__(TPB)
__attribute__((amdgpu_waves_per_eu(2, 2)))
void k_fused(const f32x4* __restrict__ e4,
             const f32x4* __restrict__ c4,
             f32x4* __restrict__ oc4,
             f32x4* __restrict__ top4,
             f32x4* __restrict__ bot4,
             float* __restrict__ partf,
             int*   __restrict__ bar) {
    __shared__ f32x4 stage[NLDS * TPB];   // 155,648 B
    __shared__ f32x4 wred[8 * 8];
    __shared__ float aptL[32];
    __shared__ f32x4 scl[8];
    __shared__ f32x4 muL[8];

    const int t    = threadIdx.x;
    const int lane = t & 63;
    const int w    = t >> 6;            // 8 waves
    const int cf   = t & 7;             // f4-col within strip
    const int r0   = t >> 3;            // 0..63
    const int s    = blockIdx.x >> 1;
    const int h    = blockIdx.x & 1;
    const int off  = s * 8 + cf;
    const size_t rbase = (size_t)h * HROWS;

    // ---- phase 1: read strip-half once; stage everything + accumulate |e|
    f32x4 reg[NREG];
    f32x4 acc = (f32x4)(0.f, 0.f, 0.f, 0.f);
    #pragma unroll
    for (int k = 0; k < NK; ++k) {
        f32x4 v = e4[(rbase + (size_t)k * 64 + r0) * DF4 + off];
        acc.x += fabsf(v.x);
        acc.y += fabsf(v.y);
        acc.z += fabsf(v.z);
        acc.w += fabsf(v.w);
        if (k < NREG) reg[k] = v;
        else          stage[(k - NREG) * TPB + t] = v;
    }
    #pragma unroll
    for (int st = 8; st <= 32; st <<= 1) {
        acc.x += __shfl_xor(acc.x, st, 64);
        acc.y += __shfl_xor(acc.y, st, 64);
        acc.z += __shfl_xor(acc.z, st, 64);
        acc.w += __shfl_xor(acc.w, st, 64);
    }
    if (lane < 8) wred[w * 8 + lane] = acc;
    __syncthreads();

    if (t < 32) {                       // publish 32-float partial, agent scope
        const int f4 = t >> 2, cm = t & 3;
        float sum = 0.f;
        #pragma unroll
        for (int w2 = 0; w2 < 8; ++w2) sum += wred[w2 * 8 + f4][cm];
        __hip_atomic_store(&partf[(size_t)blockIdx.x * 32 + t], sum,
                           __ATOMIC_RELAXED, __HIP_MEMORY_SCOPE_AGENT);
    }
    __syncthreads();

    // ---- grid barrier (bar[0] memset to 0 before every launch) ----------
    if (t == 0) {
        __hip_atomic_fetch_add(&bar[0], 1, __ATOMIC_ACQ_REL,
                               __HIP_MEMORY_SCOPE_AGENT);
        while (__hip_atomic_load(&bar[0], __ATOMIC_ACQUIRE,
                                 __HIP_MEMORY_SCOPE_AGENT) < NBLK) {}
    }
    __syncthreads();

    if (t < 32)
        aptL[t] = __hip_atomic_load(&partf[(size_t)(2 * s) * 32 + t],
                                    __ATOMIC_RELAXED, __HIP_MEMORY_SCOPE_AGENT)
                + __hip_atomic_load(&partf[(size_t)(2 * s + 1) * 32 + t],
                                    __ATOMIC_RELAXED, __HIP_MEMORY_SCOPE_AGENT);
    __syncthreads();

    // ---- finalize (redundant in both halves; 8 threads x 4 cols) --------
    if (t < 8) {
        const int g = s * 8 + t;
        const f32x4 cen = c4[g];
        f32x4 oc, cs, mu4;
        #pragma unroll
        for (int j = 0; j < 4; ++j) {
            const float apt = aptL[t * 4 + j];
            const float c  = cen[j];
            const float ub = c + apt;
            const float lb = c - apt;
            const bool cross = (ub > 0.f) && (lb < 0.f);
            const bool act   = (lb >= 0.f);
            const float denom = cross ? (ub - lb) : 1.f;
            const float slope = cross ? (ub / denom) : 0.f;
            const float mu    = cross ? (-slope * lb * 0.5f) : 0.f;
            oc[j]  = act ? c : (slope * c + mu);
            cs[j]  = act ? 1.f : slope;
            mu4[j] = mu;
        }
        scl[t] = cs;
        muL[t] = mu4;
        if (h == 0) oc4[g] = oc;
    }
    __syncthreads();

    const f32x4 cs = scl[cf];

    // ---- phase 2a: register rows -> top (pure NT write) -----------------
    #pragma unroll
    for (int k = 0; k < NREG; ++k) {
        f32x4 v = reg[k] * cs;
        __builtin_nontemporal_store(
            v, &top4[(rbase + (size_t)k * 64 + r0) * DF4 + off]);
    }
    // ---- phase 2b: LDS rows -> top (pure NT write) ----------------------
    #pragma unroll
    for (int k = NREG; k < NK; ++k) {
        f32x4 v = stage[(k - NREG) * TPB + t] * cs;
        __builtin_nontemporal_store(
            v, &top4[(rbase + (size_t)k * 64 + r0) * DF4 + off]);
    }
    // ---- phase 2c: bottom rows [32s+16h, +16) (pure NT write) -----------
    {
        const int r   = 32 * s + 16 * h + (t >> 5);
        const int dg  = r >> 2;                 // diag f4-col of row r
        const float muv = muL[(r >> 2) - 8 * s][r & 3];
        const int c0  = t & 31;
        #pragma unroll
        for (int j = 0; j < 32; ++j) {
            const int c = c0 + j * 32;
            f32x4 v = (f32x4)(0.f, 0.f, 0.f, 0.f);
            if (c == dg) v[r & 3] = muv;
            __builtin_nontemporal_store(v, &bot4[(size_t)r * DF4 + c]);
        }
    }
}

extern "C" void kernel_launch(void* const* d_in, const int* in_sizes, int n_in,
                              void* d_out, int out_size, void* d_ws, size_t ws_size,
                              hipStream_t stream) {
    const float* center = (const float*)d_in[0];   // (4096,)
    const float* error  = (const float*)d_in[1];   // (8192, 4096)
    float* out = (float*)d_out;
    float* ws  = (float*)d_ws;

    // ws: [partf: 256*32 floats = 32 KB][bar: 1 int]
    float* partf = ws;
    int*   bar   = (int*)(ws + NBLK * 32);

    float* out_center = out;                                   // (4096,)
    float* out_top    = out + D;                               // (8192, 4096)
    float* out_bottom = out + (size_t)D + (size_t)NERR * D;    // (4096, 4096)

    // Barrier counter must be 0 at kernel start on every call (ws poisoned
    // 0xAA once, never re-poisoned). Tiny async memset is graph-capture-safe.
    hipMemsetAsync(bar, 0, sizeof(int), stream);

    k_fused<<<NBLK, TPB, 0, stream>>>(
        (const f32x4*)error, (const f32x4*)center,
        (f32x4*)out_center, (f32x4*)out_top, (f32x4*)out_bottom,
        partf, bar);
}

// Round 15
// 72.227 us; speedup vs baseline: 1.2141x; 1.1822x over previous
//
#include <hip/hip_runtime.h>

#define D      4096
#define NERR   8192
#define DF4    (D / 4)          // 1024 f4 per row
#define NSTRIP 128              // strip = 32 cols = 8 f4 (128 B per row segment)
#define HROWS  (NERR / 2)       // 4096 rows per half
#define TPB    1024
#define RPP    (TPB / 8)        // 128 rows per pass
#define NPASS  (HROWS / RPP)    // 32 passes
#define NWAVE  (TPB / 64)       // 16
#define NBLK   256

typedef float f32x4 __attribute__((ext_vector_type(4)));

// ---------------- k1: partial column sums of |e|, full-line strips -----
// block b: strip s=b>>1 (f4-cols 8s..8s+8), half h=b&1 (rows 4096h..+4096).
// Wave = 8 rows x 8 f4-cols = 8 fully-used 128B lines per load instruction.
__global__ __launch_bounds__(TPB) void k_reduce(const f32x4* __restrict__ e4,
                                                f32x4* __restrict__ part4) {
    __shared__ f32x4 wred[NWAVE * 8];

    const int t    = threadIdx.x;
    const int lane = t & 63;
    const int w    = t >> 6;
    const int cf   = t & 7;             // f4-col within strip
    const int r0   = t >> 3;            // row within pass, 0..127
    const int s    = blockIdx.x >> 1;
    const int h    = blockIdx.x & 1;
    const int off  = s * 8 + cf;
    const size_t rbase = (size_t)h * HROWS;

    f32x4 acc = (f32x4)(0.f, 0.f, 0.f, 0.f);
    #pragma unroll 8
    for (int k = 0; k < NPASS; ++k) {
        f32x4 v = e4[(rbase + k * RPP + r0) * DF4 + off];
        acc.x += fabsf(v.x);
        acc.y += fabsf(v.y);
        acc.z += fabsf(v.z);
        acc.w += fabsf(v.w);
    }
    // butterfly over row bits of lane (bits 3..5); lanes keep per-cf sums
    #pragma unroll
    for (int st = 8; st <= 32; st <<= 1) {
        acc.x += __shfl_xor(acc.x, st, 64);
        acc.y += __shfl_xor(acc.y, st, 64);
        acc.z += __shfl_xor(acc.z, st, 64);
        acc.w += __shfl_xor(acc.w, st, 64);
    }
    if (lane < 8) wred[w * 8 + lane] = acc;
    __syncthreads();

    if (t < 8) {
        f32x4 sum = wred[t];
        #pragma unroll
        for (int w2 = 1; w2 < NWAVE; ++w2) sum += wred[w2 * 8 + t];
        part4[(size_t)(s * 2 + h) * 8 + t] = sum;   // 128 B per block
    }
}

// ---------------- k2: finalize + scaled top + bottom fill --------------
// Same decomposition. Finalize computed redundantly per strip pair (256 B).
// Top re-read is L3-resident. Bottom rows [32s+16h, +16) incl. diag mu.
__global__ __launch_bounds__(TPB) void k_emit(const f32x4* __restrict__ e4,
                                              const f32x4* __restrict__ part4,
                                              const f32x4* __restrict__ c4,
                                              f32x4* __restrict__ oc4,
                                              f32x4* __restrict__ top4,
                                              f32x4* __restrict__ bot4) {
    __shared__ f32x4 scl[8];
    __shared__ f32x4 muL[8];

    const int t    = threadIdx.x;
    const int cf   = t & 7;
    const int r0   = t >> 3;
    const int s    = blockIdx.x >> 1;
    const int h    = blockIdx.x & 1;
    const int off  = s * 8 + cf;
    const size_t rbase = (size_t)h * HROWS;

    // ---- finalize: 8 threads, one f4-col (4 columns) each
    if (t < 8) {
        const int g = s * 8 + t;
        const f32x4 apt = part4[(size_t)(s * 2) * 8 + t]
                        + part4[(size_t)(s * 2 + 1) * 8 + t];
        const f32x4 cen = c4[g];
        f32x4 oc, cs, mu4;
        #pragma unroll
        for (int j = 0; j < 4; ++j) {
            const float c  = cen[j];
            const float ub = c + apt[j];
            const float lb = c - apt[j];
            const bool cross = (ub > 0.f) && (lb < 0.f);
            const bool act   = (lb >= 0.f);
            const float denom = cross ? (ub - lb) : 1.f;
            const float slope = cross ? (ub / denom) : 0.f;
            const float mu    = cross ? (-slope * lb * 0.5f) : 0.f;
            oc[j]  = act ? c : (slope * c + mu);
            cs[j]  = act ? 1.f : slope;
            mu4[j] = mu;
        }
        scl[t] = cs;
        muL[t] = mu4;
        if (h == 0) oc4[g] = oc;
    }
    __syncthreads();

    // ---- top: re-read own half (L3 hit), scale, NT store
    const f32x4 cs = scl[cf];
    #pragma unroll 8
    for (int k = 0; k < NPASS; ++k) {
        const size_t idx = (rbase + k * RPP + r0) * DF4 + off;
        f32x4 v = e4[idx];
        v *= cs;
        __builtin_nontemporal_store(v, &top4[idx]);
    }

    // ---- bottom: rows [32s+16h, +16), one wave per row; diag f4 = mu
    const int w    = t >> 6;
    const int lane = t & 63;
    const int r    = 32 * s + 16 * h + w;
    const int dg   = r >> 2;                    // diag f4-col of row r
    const float muv = muL[(r >> 2) - 8 * s][r & 3];
    #pragma unroll
    for (int j = 0; j < 16; ++j) {
        const int c = lane + j * 64;
        f32x4 v = (f32x4)(0.f, 0.f, 0.f, 0.f);
        if (c == dg) v[r & 3] = muv;
        __builtin_nontemporal_store(v, &bot4[(size_t)r * DF4 + c]);
    }
}

extern "C" void kernel_launch(void* const* d_in, const int* in_sizes, int n_in,
                              void* d_out, int out_size, void* d_ws, size_t ws_size,
                              hipStream_t stream) {
    const float* center = (const float*)d_in[0];   // (4096,)
    const float* error  = (const float*)d_in[1];   // (8192, 4096)
    float* out = (float*)d_out;

    float* out_center = out;                                   // (4096,)
    float* out_top    = out + D;                               // (8192, 4096)
    float* out_bottom = out + (size_t)D + (size_t)NERR * D;    // (4096, 4096)

    f32x4* part4 = (f32x4*)d_ws;   // 256 blocks x 128 B = 32 KB

    k_reduce<<<NBLK, TPB, 0, stream>>>(
        (const f32x4*)error, part4);
    k_emit<<<NBLK, TPB, 0, stream>>>(
        (const f32x4*)error, part4, (const f32x4*)center,
        (f32x4*)out_center, (f32x4*)out_top, (f32x4*)out_bottom);
}